// Round 12
// baseline (176.234 us; speedup 1.0000x reference)
//
#include <hip/hip_runtime.h>

#define HIDDEN 128
#define NRAD 6
#define NEMB 95
#define PRS 68    // pps row stride in words (64-ch slice + 4 pad): banks rotate by 4
#define FRS 132   // fragS row stride in shorts (264 B)
#define SRS 36    // stage row stride in ushorts (72 B)

typedef short bf16x8 __attribute__((ext_vector_type(8)));
typedef float f32x4 __attribute__((ext_vector_type(4)));

__device__ __forceinline__ float fast_rcp(float x) { return __builtin_amdgcn_rcpf(x); }
__device__ __forceinline__ float swishf(float v) { return v * fast_rcp(1.0f + __expf(-v)); }
// float -> bf16 (round-to-nearest-even)
__device__ __forceinline__ short f2bf(float f) {
    union { float f; unsigned u; } c; c.f = f;
    unsigned r = (c.u + 0x7FFFu + ((c.u >> 16) & 1u)) >> 16;
    return (short)(unsigned short)r;
}
__device__ __forceinline__ float bf2f(unsigned short u) {
    union { unsigned u; float f; } c; c.u = ((unsigned)u) << 16; return c.f;
}
// pack two floats to packed-bf16 (truncated) in one v_perm_b32
__device__ __forceinline__ unsigned pk(float lo, float hi) {
    return __builtin_amdgcn_perm(__float_as_uint(hi), __float_as_uint(lo), 0x07060302u);
}
__device__ __forceinline__ float xlo(unsigned u) {
    union { unsigned u; float f; } c; c.u = u << 16; return c.f;
}
__device__ __forceinline__ float xhi(unsigned u) {
    union { unsigned u; float f; } c; c.u = u & 0xffff0000u; return c.f;
}
__device__ __forceinline__ void barrier_lgkm() {
    asm volatile("s_waitcnt lgkmcnt(0)" ::: "memory");
    __builtin_amdgcn_s_barrier();
}
__device__ __forceinline__ void wait_lgkm() {
    asm volatile("s_waitcnt lgkmcnt(0)" ::: "memory");
}

// pPair[a][h] = (bf16(P2[a][h]) << 16) | bf16(P1[a][h])
__global__ void precompute_kernel(const float* __restrict__ emb,
                                  const float* __restrict__ w_lin,
                                  const float* __restrict__ b_lin,
                                  unsigned* __restrict__ pPair) {
    __shared__ __align__(16) float erow[HIDDEN];
    const int a = blockIdx.x;
    const int h = threadIdx.x;
    erow[h] = emb[a * HIDDEN + h];
    __syncthreads();
    float a1 = b_lin[h];
    float a2 = 0.f;
    const float* __restrict__ w1 = w_lin + h * 384;
    const float* __restrict__ w2 = w1 + HIDDEN;
#pragma unroll 8
    for (int k = 0; k < HIDDEN; ++k) {
        a1 += erow[k] * w1[k];
        a2 += erow[k] * w2[k];
    }
    const unsigned lo = (unsigned)(unsigned short)f2bf(a1);
    const unsigned hi = ((unsigned)(unsigned short)f2bf(a2)) << 16;
    pPair[a * HIDDEN + h] = hi | lo;
}

struct RawMD {
    float2 ra, rb, rc;   // rbf[e][0..5]
    int ii, jj;          // iv[e], jv[e]
};

__device__ __forceinline__ RawMD load_raw(int st, int l15, int n_edges,
                                          const int* __restrict__ iv,
                                          const int* __restrict__ jv,
                                          const float* __restrict__ rbf) {
    int e = st * 16 + l15;
    int ecl = (e < n_edges) ? e : (n_edges - 1);
    RawMD m;
    const float2* rp = reinterpret_cast<const float2*>(rbf + (size_t)ecl * NRAD);
    m.ra = rp[0];
    m.rb = rp[1];
    m.rc = rp[2];
    m.ii = iv[ecl];
    m.jj = jv[ecl];
    return m;
}

// Channel-split blocks: block handles a 64-ch slice (chh = bid&1) of 32 edges
// per iteration -> LDS ~44 KB -> 3 blocks/CU (3 waves/SIMD).
// Wave roles: u = wid>>1 (16-edge subtile it outputs), c2 = wid&1 (32-ch half).
// rbf0 A-build via MFMA: w0ext rows [w0, b0, 0] x rpad [rbf, 1, 0] -> fragS
// (wave builds slab ks=wid for both subtiles).  Main MFMA: A = W3 rows (regs),
// B = fragS.  In-wave full-128B-line stores one tile behind via bf16 stage.
__global__ __launch_bounds__(256, 3)
void edge_mfma_kernel(const int* __restrict__ xv,
                      const float* __restrict__ rbf,
                      const int* __restrict__ iv,
                      const int* __restrict__ jv,
                      const float* __restrict__ w_rbf0,
                      const float* __restrict__ b_rbf0,
                      const float* __restrict__ w_rbf1,
                      const float* __restrict__ w_lin,
                      const unsigned* __restrict__ pPairG,
                      float* __restrict__ out_e1,
                      float* __restrict__ out_e2,
                      int n_edges, int tiles_per_block, int nt32, int n_rows) {
    __shared__ unsigned pps[NEMB * PRS];                        // 25840 B
    __shared__ __align__(16) short fragS[2][16 * FRS];          // 8448 B
    __shared__ __align__(8) unsigned short stg[4][2][16 * SRS]; // 9216 B

    const int tid = threadIdx.x;
    const int chh = blockIdx.x & 1;     // which 64-ch half of HIDDEN
    const int ebi = blockIdx.x >> 1;    // edge-range block index

    // ---- stage packed P slice (cols [64*chh, 64*chh+64)) ----
    {
        const int nr = (n_rows < NEMB ? n_rows : NEMB);
        for (int s = tid; s < nr * 64; s += 256) {
            const int a = s >> 6, c = s & 63;
            pps[a * PRS + c] = pPairG[a * HIDDEN + chh * 64 + c];
        }
    }

    const int wid = tid >> 6;
    const int lane = tid & 63;
    const int l15 = lane & 15;
    const int lg = lane >> 4;
    const int u = wid >> 1;             // subtile this wave owns
    const int c2 = wid & 1;             // 32-ch half within the slice
    const int chbase = chh * 64 + c2 * 32;

    // ---- W3 + w1 fragments in registers (rows h = chbase + n2*16 + l15) ----
    bf16x8 w3f[2][4];
    bf16x8 w1f[2];
#pragma unroll
    for (int n2 = 0; n2 < 2; ++n2) {
        const int h = chbase + n2 * 16 + l15;
        const float* wp = w_lin + h * 384 + 256;
#pragma unroll
        for (int ks = 0; ks < 4; ++ks) {
            const float4* s4 = reinterpret_cast<const float4*>(wp + (ks * 4 + lg) * 8);
            const float4 va = s4[0];
            const float4 vb = s4[1];
            bf16x8 fr;
            fr[0] = f2bf(va.x); fr[1] = f2bf(va.y);
            fr[2] = f2bf(va.z); fr[3] = f2bf(va.w);
            fr[4] = f2bf(vb.x); fr[5] = f2bf(vb.y);
            fr[6] = f2bf(vb.z); fr[7] = f2bf(vb.w);
            w3f[n2][ks] = fr;
        }
        bf16x8 f1;
#pragma unroll
        for (int r = 0; r < NRAD; ++r) f1[r] = f2bf(w_rbf1[h * NRAD + r]);
        f1[6] = 0; f1[7] = 0;
        w1f[n2] = f1;
    }

    // ---- w0ext A-fragments for slab ks=wid (k in [32*wid, 32*wid+32)) ----
    bf16x8 aw0[2];
#pragma unroll
    for (int i = 0; i < 2; ++i) {
        bf16x8 fr = (bf16x8){0, 0, 0, 0, 0, 0, 0, 0};
        if (lg == 0) {
            const int k = (2 * wid + i) * 16 + l15;
#pragma unroll
            for (int r = 0; r < NRAD; ++r) fr[r] = f2bf(w_rbf0[k * NRAD + r]);
            fr[6] = f2bf(b_rbf0[k]);   // bias folded: rpad carries 1.0 at r=6
            fr[7] = 0;
        }
        aw0[i] = fr;
    }
    __syncthreads();   // pps staged

    const int bt = ebi * tiles_per_block;
    const int btEnd = min(bt + tiles_per_block, nt32);
    if (bt >= btEnd) return;   // uniform per block

    const f32x4 zero4 = (f32x4){0.f, 0.f, 0.f, 0.f};

    RawMD c0 = load_raw(2 * bt,     l15, n_edges, iv, jv, rbf);
    RawMD c1 = load_raw(2 * bt + 1, l15, n_edges, iv, jv, rbf);

    for (int t = bt; t < btEnd; ++t) {
        // prefetch next tile's raw MD (consumed next iteration)
        RawMD n0 = load_raw(2 * (t + 1),     l15, n_edges, iv, jv, rbf);
        RawMD n1 = load_raw(2 * (t + 1) + 1, l15, n_edges, iv, jv, rbf);
        // xv gathers for this wave's subtile (used in late epilogue)
        const int exi = xv[u ? c1.ii : c0.ii];
        const int exj = xv[u ? c1.jj : c0.jj];

        // ---- rpad (B-operand) for both subtiles: [rbf, 1, 0] in lg==0 ----
        union { uint4 q; bf16x8 b; } rp0, rp1;
        rp0.q = (uint4){0u, 0u, 0u, 0u};
        rp1.q = (uint4){0u, 0u, 0u, 0u};
        if (lg == 0) {
            rp0.q.x = pk(c0.ra.x, c0.ra.y);
            rp0.q.y = pk(c0.rb.x, c0.rb.y);
            rp0.q.z = pk(c0.rc.x, c0.rc.y);
            rp0.q.w = pk(1.0f, 0.0f);
            rp1.q.x = pk(c1.ra.x, c1.ra.y);
            rp1.q.y = pk(c1.rb.x, c1.rb.y);
            rp1.q.z = pk(c1.rc.x, c1.rc.y);
            rp1.q.w = pk(1.0f, 0.0f);
        }

        // ---- A-build via MFMA: slab ks=wid for both subtiles ----
#pragma unroll
        for (int s = 0; s < 2; ++s) {
#pragma unroll
            for (int i = 0; i < 2; ++i) {
                const f32x4 cb = __builtin_amdgcn_mfma_f32_16x16x32_bf16(
                    aw0[i], (s ? rp1.b : rp0.b), zero4, 0, 0, 0);
                const uint2 wv = make_uint2(pk(swishf(cb[0]), swishf(cb[1])),
                                            pk(swishf(cb[2]), swishf(cb[3])));
                // chunk c = 4*ntk + lg ; row = edge l15
                *reinterpret_cast<uint2*>(
                    &fragS[s][l15 * FRS + (4 * (2 * wid + i) + lg) * 4]) = wv;
            }
        }

        // ---- qd = rbf @ w1^T for own subtile (w1f[6..7]=0, rpad r=6 harmless) ----
        f32x4 acc2[2];
#pragma unroll
        for (int n2 = 0; n2 < 2; ++n2)
            acc2[n2] = __builtin_amdgcn_mfma_f32_16x16x32_bf16(
                w1f[n2], (u ? rp1.b : rp0.b), zero4, 0, 0, 0);

        barrier_lgkm();   // bar1: fragS slabs visible

        f32x4 acc[2] = {zero4, zero4};
#pragma unroll
        for (int ks = 0; ks < 4; ++ks) {
            const bf16x8 bf = *reinterpret_cast<const bf16x8*>(
                &fragS[u][l15 * FRS + (8 * ks + 2 * lg) * 4]);
#pragma unroll
            for (int n2 = 0; n2 < 2; ++n2)
                acc[n2] = __builtin_amdgcn_mfma_f32_16x16x32_bf16(
                    w3f[n2][ks], bf, acc[n2], 0, 0, 0);
        }

        barrier_lgkm();   // bar2: all fragS reads drained -> next iter may overwrite

        // ---- store phase for tile t-1 (in-wave, full 128B lines) ----
        if (t != bt) {
            const int tp = t - 1;
#pragma unroll
            for (int arr = 0; arr < 2; ++arr) {
                float* __restrict__ ob = arr ? out_e2 : out_e1;
#pragma unroll
                for (int s = 0; s < 2; ++s) {
                    const int e = 8 * s + (lane >> 3);
                    const uint2 uv = *reinterpret_cast<const uint2*>(
                        &stg[wid][arr][e * SRS + (lane & 7) * 4]);
                    const int eg = tp * 32 + u * 16 + e;
                    if (eg < n_edges) {
                        f32x4 v;
                        v[0] = xlo(uv.x); v[1] = xhi(uv.x);
                        v[2] = xlo(uv.y); v[3] = xhi(uv.y);
                        *reinterpret_cast<f32x4*>(
                            ob + (size_t)eg * HIDDEN + chbase + (lane & 7) * 4) = v;
                    }
                }
            }
        }
        wait_lgkm();   // in-wave WAR: stage reads complete before overwrite

        // ---- epilogue: P adds, swish, e2, per-wave bf16 stage writes ----
#pragma unroll
        for (int n2 = 0; n2 < 2; ++n2) {
            const int ch0 = c2 * 32 + n2 * 16 + lg * 4;   // within 64-ch slice
            const uint4 r1 = *reinterpret_cast<const uint4*>(&pps[exi * PRS + ch0]);
            const uint4 r2 = *reinterpret_cast<const uint4*>(&pps[exj * PRS + ch0]);
            float pv[4];
            pv[0] = bf2f((unsigned short)(r1.x & 0xffff)) + bf2f((unsigned short)(r2.x >> 16));
            pv[1] = bf2f((unsigned short)(r1.y & 0xffff)) + bf2f((unsigned short)(r2.y >> 16));
            pv[2] = bf2f((unsigned short)(r1.z & 0xffff)) + bf2f((unsigned short)(r2.z >> 16));
            pv[3] = bf2f((unsigned short)(r1.w & 0xffff)) + bf2f((unsigned short)(r2.w >> 16));
            float e1v[4], e2v[4];
#pragma unroll
            for (int q = 0; q < 4; ++q) {
                const float sm = acc[n2][q] + pv[q];
                e1v[q] = swishf(sm);
                e2v[q] = acc2[n2][q] * e1v[q];
            }
            const int so = l15 * SRS + n2 * 16 + lg * 4;
            *reinterpret_cast<uint2*>(&stg[wid][0][so]) =
                make_uint2(pk(e1v[0], e1v[1]), pk(e1v[2], e1v[3]));
            *reinterpret_cast<uint2*>(&stg[wid][1][so]) =
                make_uint2(pk(e2v[0], e2v[1]), pk(e2v[2], e2v[3]));
        }

        c0 = n0; c1 = n1;
    }

    // ---- drain: store phase for the last tile ----
    wait_lgkm();
    {
        const int tp = btEnd - 1;
#pragma unroll
        for (int arr = 0; arr < 2; ++arr) {
            float* __restrict__ ob = arr ? out_e2 : out_e1;
#pragma unroll
            for (int s = 0; s < 2; ++s) {
                const int e = 8 * s + (lane >> 3);
                const uint2 uv = *reinterpret_cast<const uint2*>(
                    &stg[wid][arr][e * SRS + (lane & 7) * 4]);
                const int eg = tp * 32 + u * 16 + e;
                if (eg < n_edges) {
                    f32x4 v;
                    v[0] = xlo(uv.x); v[1] = xhi(uv.x);
                    v[2] = xlo(uv.y); v[3] = xhi(uv.y);
                    *reinterpret_cast<f32x4*>(
                        ob + (size_t)eg * HIDDEN + chbase + (lane & 7) * 4) = v;
                }
            }
        }
    }
}

extern "C" void kernel_launch(void* const* d_in, const int* in_sizes, int n_in,
                              void* d_out, int out_size, void* d_ws, size_t ws_size,
                              hipStream_t stream) {
    const int*   xv     = (const int*)  d_in[0];
    const float* rbf    = (const float*)d_in[1];
    const int*   iv     = (const int*)  d_in[2];
    const int*   jv     = (const int*)  d_in[3];
    const float* emb    = (const float*)d_in[4];
    const float* w_rbf0 = (const float*)d_in[5];
    const float* b_rbf0 = (const float*)d_in[6];
    const float* w_lin  = (const float*)d_in[7];
    const float* b_lin  = (const float*)d_in[8];
    const float* w_rbf1 = (const float*)d_in[9];

    const int n_edges = in_sizes[2];
    const int n_emb_rows = in_sizes[4] / HIDDEN;   // 95

    unsigned* pPair = (unsigned*)d_ws;             // 95*128*4 = 48640 B

    float* out_e1 = (float*)d_out;
    float* out_e2 = out_e1 + (size_t)n_edges * HIDDEN;

    precompute_kernel<<<n_emb_rows, HIDDEN, 0, stream>>>(emb, w_lin, b_lin, pPair);

    const int nt32 = (n_edges + 31) / 32;
    const int grid = 768;                          // 3 blocks/CU, 2 ch-slices/tile
    const int nEB = grid / 2;                      // 384 edge-range blocks
    const int tpb = (nt32 + nEB - 1) / nEB;
    edge_mfma_kernel<<<grid, 256, 0, stream>>>(xv, rbf, iv, jv,
                                               w_rbf0, b_rbf0, w_rbf1, w_lin,
                                               pPair, out_e1, out_e2,
                                               n_edges, tpb, nt32, n_emb_rows);
}

// Round 13
// 155.787 us; speedup vs baseline: 1.1313x; 1.1313x over previous
//
#include <hip/hip_runtime.h>

#define HIDDEN 128
#define NRAD 6
#define NEMB 95
#define PRS 132   // pps row stride (words)
#define WRS 132   // w3s row stride (shorts)
#define SRS 132   // stage row stride (shorts)
#define NWAVES 12
#define NBLK 256

typedef short bf16x8 __attribute__((ext_vector_type(8)));
typedef float f32x4 __attribute__((ext_vector_type(4)));

__device__ __forceinline__ float fast_rcp(float x) { return __builtin_amdgcn_rcpf(x); }
__device__ __forceinline__ float swishf(float v) { return v * fast_rcp(1.0f + __expf(-v)); }
// float -> bf16 (round-to-nearest-even)
__device__ __forceinline__ short f2bf(float f) {
    union { float f; unsigned u; } c; c.f = f;
    unsigned r = (c.u + 0x7FFFu + ((c.u >> 16) & 1u)) >> 16;
    return (short)(unsigned short)r;
}
__device__ __forceinline__ float bf2f(unsigned short u) {
    union { unsigned u; float f; } c; c.u = ((unsigned)u) << 16; return c.f;
}
// pack two floats to packed-bf16 (truncated) in one v_perm_b32
__device__ __forceinline__ unsigned pk(float lo, float hi) {
    return __builtin_amdgcn_perm(__float_as_uint(hi), __float_as_uint(lo), 0x07060302u);
}
__device__ __forceinline__ float xlo(unsigned u) {
    union { unsigned u; float f; } c; c.u = u << 16; return c.f;
}
__device__ __forceinline__ float xhi(unsigned u) {
    union { unsigned u; float f; } c; c.u = u & 0xffff0000u; return c.f;
}
__device__ __forceinline__ void wait_lgkm() {
    asm volatile("s_waitcnt lgkmcnt(0)" ::: "memory");
}

// pPair[a][h] = (bf16(P2[a][h]) << 16) | bf16(P1[a][h])
__global__ void precompute_kernel(const float* __restrict__ emb,
                                  const float* __restrict__ w_lin,
                                  const float* __restrict__ b_lin,
                                  unsigned* __restrict__ pPair) {
    __shared__ __align__(16) float erow[HIDDEN];
    const int a = blockIdx.x;
    const int h = threadIdx.x;
    erow[h] = emb[a * HIDDEN + h];
    __syncthreads();
    float a1 = b_lin[h];
    float a2 = 0.f;
    const float* __restrict__ w1 = w_lin + h * 384;
    const float* __restrict__ w2 = w1 + HIDDEN;
#pragma unroll 8
    for (int k = 0; k < HIDDEN; ++k) {
        a1 += erow[k] * w1[k];
        a2 += erow[k] * w2[k];
    }
    const unsigned lo = (unsigned)(unsigned short)f2bf(a1);
    const unsigned hi = ((unsigned)(unsigned short)f2bf(a2)) << 16;
    pPair[a * HIDDEN + h] = hi | lo;
}

struct RawMD {
    float2 ra, rb, rc;   // rbf[e][0..5]
    int ii, jj;          // iv[e], jv[e]
};

__device__ __forceinline__ RawMD load_raw(int tile, int l15, int n_edges,
                                          const int* __restrict__ iv,
                                          const int* __restrict__ jv,
                                          const float* __restrict__ rbf) {
    int e = tile * 16 + l15;
    int ecl = (e < n_edges) ? e : (n_edges - 1);
    RawMD m;
    const float2* rp = reinterpret_cast<const float2*>(rbf + (size_t)ecl * NRAD);
    m.ra = rp[0];
    m.rb = rp[1];
    m.rc = rp[2];
    m.ii = iv[ecl];
    m.jj = jv[ecl];
    return m;
}

// BARRIER-FREE wave-local kernel: each wave owns a 16-edge tile end-to-end.
// Lane (lg,l15) builds rbf0 B-fragments for (e=l15, k=ks*32+lg*8+j) from
// broadcast b128 reads of w0ext (each (k,e) computed exactly once - no
// redundancy, no exchange).  A = W3 rows / w1 rows from LDS.  P1/P2 packed
// bf16 in LDS.  Stores via per-wave bf16 stage (in-wave lgkm ordering, NO
// s_barrier) in two 8-edge passes -> 1KB-contiguous full-line bursts.
// One 768-thread block per CU shares the tables; 12 waves free-run.
__global__ __launch_bounds__(768)
void edge_mfma_kernel(const int* __restrict__ xv,
                      const float* __restrict__ rbf,
                      const int* __restrict__ iv,
                      const int* __restrict__ jv,
                      const float* __restrict__ w_rbf0,
                      const float* __restrict__ b_rbf0,
                      const float* __restrict__ w_rbf1,
                      const float* __restrict__ w_lin,
                      const unsigned* __restrict__ pPairG,
                      float* __restrict__ out_e1,
                      float* __restrict__ out_e2,
                      int n_edges, int nt16, int n_rows) {
    __shared__ unsigned pps[NEMB * PRS];                           // 50160 B
    __shared__ __align__(16) short w3s[HIDDEN * WRS];              // 33792 B
    __shared__ __align__(16) float w0e[HIDDEN * 8];                //  4096 B
    __shared__ __align__(16) short w1a[HIDDEN * 8];                //  2048 B
    __shared__ __align__(8) unsigned short stg[NWAVES][2][8 * SRS]; // 50688 B

    const int tid = threadIdx.x;

    // ---- stage packed P table (padded rows) ----
    {
        const int nr = (n_rows < NEMB ? n_rows : NEMB);
        for (int s = tid; s < nr * HIDDEN; s += 768) {
            const int a = s >> 7, c = s & 127;
            pps[a * PRS + c] = pPairG[s];
        }
    }
    // ---- stage W3 bf16 (row h, 16 octets of 8 k) ----
    for (int s = tid; s < HIDDEN * 16; s += 768) {
        const int h = s >> 4, oct = s & 15;
        const float4* s4 = reinterpret_cast<const float4*>(w_lin + h * 384 + 256 + oct * 8);
        const float4 va = s4[0];
        const float4 vb = s4[1];
        bf16x8 fr;
        fr[0] = f2bf(va.x); fr[1] = f2bf(va.y);
        fr[2] = f2bf(va.z); fr[3] = f2bf(va.w);
        fr[4] = f2bf(vb.x); fr[5] = f2bf(vb.y);
        fr[6] = f2bf(vb.z); fr[7] = f2bf(vb.w);
        *reinterpret_cast<bf16x8*>(&w3s[h * WRS + oct * 8]) = fr;
    }
    // ---- w0ext rows [w0[k][0..5], b0[k], 0] f32 ; w1 rows bf16 ----
    if (tid < HIDDEN) {
        const int k = tid;
#pragma unroll
        for (int r = 0; r < NRAD; ++r) w0e[k * 8 + r] = w_rbf0[k * NRAD + r];
        w0e[k * 8 + 6] = b_rbf0[k];
        w0e[k * 8 + 7] = 0.f;
        bf16x8 f1;
#pragma unroll
        for (int r = 0; r < NRAD; ++r) f1[r] = f2bf(w_rbf1[k * NRAD + r]);
        f1[6] = 0; f1[7] = 0;
        *reinterpret_cast<bf16x8*>(&w1a[k * 8]) = f1;
    }
    __syncthreads();   // the ONLY block barrier

    const int wid = tid >> 6;
    const int lane = tid & 63;
    const int l15 = lane & 15;
    const int lg = lane >> 4;
    const int gw = blockIdx.x * NWAVES + wid;
    const int NW = NBLK * NWAVES;

    const f32x4 zero4 = (f32x4){0.f, 0.f, 0.f, 0.f};

    int t = gw;
    if (t < nt16) {
        RawMD cur = load_raw(t, l15, n_edges, iv, jv, rbf);
        for (; t < nt16; t += NW) {
            const int tn = (t + NW < nt16) ? t + NW : t;
            RawMD nxt = load_raw(tn, l15, n_edges, iv, jv, rbf);   // prefetch
            const int xi = xv[cur.ii];
            const int xj = xv[cur.jj];

            // ---- A-build: lane's own (e=l15, k=ks*32+lg*8+j), b128 broadcasts ----
            bf16x8 bfrag[4];
#pragma unroll
            for (int ks = 0; ks < 4; ++ks) {
                float sv[8];
#pragma unroll
                for (int j = 0; j < 8; ++j) {
                    const int k = ks * 32 + lg * 8 + j;
                    const f32x4 wa = *reinterpret_cast<const f32x4*>(&w0e[k * 8]);
                    const f32x4 wb = *reinterpret_cast<const f32x4*>(&w0e[k * 8 + 4]);
                    const float tv = wb[2]
                                   + cur.ra.x * wa[0] + cur.ra.y * wa[1]
                                   + cur.rb.x * wa[2] + cur.rb.y * wa[3]
                                   + cur.rc.x * wb[0] + cur.rc.y * wb[1];
                    sv[j] = swishf(tv);
                }
                union { uint4 q; bf16x8 b; } mf;
                mf.q.x = pk(sv[0], sv[1]); mf.q.y = pk(sv[2], sv[3]);
                mf.q.z = pk(sv[4], sv[5]); mf.q.w = pk(sv[6], sv[7]);
                bfrag[ks] = mf.b;
            }

            // ---- qd = rbf @ w1^T via MFMA (rpad [rbf,1,0] in lg==0) ----
            union { uint4 q; bf16x8 b; } rp;
            rp.q = (uint4){0u, 0u, 0u, 0u};
            if (lg == 0) {
                rp.q.x = pk(cur.ra.x, cur.ra.y);
                rp.q.y = pk(cur.rb.x, cur.rb.y);
                rp.q.z = pk(cur.rc.x, cur.rc.y);
                rp.q.w = pk(1.0f, 0.0f);
            }
            f32x4 acc2[8];
#pragma unroll
            for (int nt = 0; nt < 8; ++nt) {
                const bf16x8 aw = *reinterpret_cast<const bf16x8*>(
                    &w1a[(nt * 16 + l15) * 8]);
                acc2[nt] = __builtin_amdgcn_mfma_f32_16x16x32_bf16(aw, rp.b, zero4, 0, 0, 0);
            }

            // ---- main MFMA: C[ch][e], lane -> (e=l15, ch=nt*16+lg*4+q) ----
            f32x4 acc[8];
#pragma unroll
            for (int nt = 0; nt < 8; ++nt) acc[nt] = zero4;
#pragma unroll
            for (int ks = 0; ks < 4; ++ks)
#pragma unroll
                for (int nt = 0; nt < 8; ++nt) {
                    const bf16x8 wfr = *reinterpret_cast<const bf16x8*>(
                        &w3s[(nt * 16 + l15) * WRS + (ks * 4 + lg) * 8]);
                    acc[nt] = __builtin_amdgcn_mfma_f32_16x16x32_bf16(
                        wfr, bfrag[ks], acc[nt], 0, 0, 0);
                }

            // ---- epilogue + stores: two 8-edge passes through per-wave stage ----
#pragma unroll
            for (int p = 0; p < 2; ++p) {
                if ((l15 >> 3) == p) {
                    const int so = (l15 & 7) * SRS;
#pragma unroll
                    for (int nt = 0; nt < 8; ++nt) {
                        const int ch0 = nt * 16 + lg * 4;
                        const uint4 r1 = *reinterpret_cast<const uint4*>(&pps[xi * PRS + ch0]);
                        const uint4 r2 = *reinterpret_cast<const uint4*>(&pps[xj * PRS + ch0]);
                        float e1v[4], e2v[4];
                        {
                            const unsigned rr1[4] = {r1.x, r1.y, r1.z, r1.w};
                            const unsigned rr2[4] = {r2.x, r2.y, r2.z, r2.w};
#pragma unroll
                            for (int q = 0; q < 4; ++q) {
                                const float pv = bf2f((unsigned short)(rr1[q] & 0xffff))
                                               + bf2f((unsigned short)(rr2[q] >> 16));
                                const float sm = acc[nt][q] + pv;
                                e1v[q] = swishf(sm);
                                e2v[q] = acc2[nt][q] * e1v[q];
                            }
                        }
                        *reinterpret_cast<uint2*>(&stg[wid][0][so + ch0]) =
                            make_uint2(pk(e1v[0], e1v[1]), pk(e1v[2], e1v[3]));
                        *reinterpret_cast<uint2*>(&stg[wid][1][so + ch0]) =
                            make_uint2(pk(e2v[0], e2v[1]), pk(e2v[2], e2v[3]));
                    }
                }
                wait_lgkm();   // in-wave: stage writes complete before reads

                const size_t base = ((size_t)t * 16 + p * 8) * HIDDEN;
#pragma unroll
                for (int arr = 0; arr < 2; ++arr) {
                    float* __restrict__ ob = arr ? out_e2 : out_e1;
#pragma unroll
                    for (int s2 = 0; s2 < 4; ++s2) {
                        const int idx = s2 * 256 + lane * 4;   // floats within 4KB
                        const int e_l = idx >> 7;
                        const int ch = idx & 127;
                        const uint2 uv = *reinterpret_cast<const uint2*>(
                            &stg[wid][arr][e_l * SRS + ch]);
                        if (t * 16 + p * 8 + e_l < n_edges) {
                            f32x4 v;
                            v[0] = xlo(uv.x); v[1] = xhi(uv.x);
                            v[2] = xlo(uv.y); v[3] = xhi(uv.y);
                            *reinterpret_cast<f32x4*>(ob + base + idx) = v;
                        }
                    }
                }
                wait_lgkm();   // in-wave WAR: stage reads drained before next pass
            }
            cur = nxt;
        }
    }
}

extern "C" void kernel_launch(void* const* d_in, const int* in_sizes, int n_in,
                              void* d_out, int out_size, void* d_ws, size_t ws_size,
                              hipStream_t stream) {
    const int*   xv     = (const int*)  d_in[0];
    const float* rbf    = (const float*)d_in[1];
    const int*   iv     = (const int*)  d_in[2];
    const int*   jv     = (const int*)  d_in[3];
    const float* emb    = (const float*)d_in[4];
    const float* w_rbf0 = (const float*)d_in[5];
    const float* b_rbf0 = (const float*)d_in[6];
    const float* w_lin  = (const float*)d_in[7];
    const float* b_lin  = (const float*)d_in[8];
    const float* w_rbf1 = (const float*)d_in[9];

    const int n_edges = in_sizes[2];
    const int n_emb_rows = in_sizes[4] / HIDDEN;   // 95

    unsigned* pPair = (unsigned*)d_ws;             // 95*128*4 = 48640 B

    float* out_e1 = (float*)d_out;
    float* out_e2 = out_e1 + (size_t)n_edges * HIDDEN;

    precompute_kernel<<<n_emb_rows, HIDDEN, 0, stream>>>(emb, w_lin, b_lin, pPair);

    const int nt16 = (n_edges + 15) / 16;
    edge_mfma_kernel<<<NBLK, 768, 0, stream>>>(xv, rbf, iv, jv,
                                               w_rbf0, b_rbf0, w_rbf1, w_lin,
                                               pPair, out_e1, out_e2,
                                               n_edges, nt16, n_emb_rows);
}